// Round 10
// baseline (187.928 us; speedup 1.0000x reference)
//
#include <hip/hip_runtime.h>

// Attention_13632226198096: B=4, S=2048, D=1024 fp32 single-head attention.
// Round 10: ring_gemm — 256x256 tile, BK=32, RING-4 LDS buffers (128 KB),
// stage tile t+3 while computing t (3-tile latency cover), vmcnt(8) steady,
// ONE barrier/tile. Per-wave 128x64 output (MFMA-bound LDS intensity).
// BK=32 rows (64B) make ds_read_b128 frags bank-balanced -> linear LDS,
// no swizzle. Used for proj (MODE 2: q/k/vt split) and QK (MODE 1: fp16).
// PV / softmax / casts unchanged from r9.

typedef unsigned short ushort_t;
typedef __bf16 bf16x8 __attribute__((ext_vector_type(8)));
typedef float f32x4 __attribute__((ext_vector_type(4)));
typedef _Float16 h8 __attribute__((ext_vector_type(8)));
typedef short short8v __attribute__((ext_vector_type(8)));

__device__ __forceinline__ unsigned short f2bf(float f) {
  unsigned u = __builtin_bit_cast(unsigned, f);
  u += 0x7fffu + ((u >> 16) & 1u);
  return (unsigned short)(u >> 16);
}

// ---------------------------------------------------------------------------
// ring_gemm: C = scale*(A @ B^T) + bias; 256x256 tile, BK=32, 512 thr
// (8 waves 2Mx4N, per-wave 128x64). Ring-4 K-tile buffers.
// Protocol per tile t: stage(t+3) -> ds_read frags of ring[t&3] -> 32 MFMA
// -> vmcnt(8) [certifies t+1] -> s_barrier.
// Slot reuse gap = 3 tiles; readers of a slot finish before that tile's end
// barrier, stage of the slot is >=2 barriers later => race-free.
// MODE 1: fp16 C0 (scaled). MODE 2: proj split q/k bf16 + v^T into vt.
// ---------------------------------------------------------------------------
template<int MODE, int RX, int RY>
__global__ __launch_bounds__(512, 1)
void ring_gemm(const ushort_t* __restrict__ A, long long sAz, int lda,
               const ushort_t* __restrict__ Bm, long long sBz, int ldb,
               void* __restrict__ C0, void* __restrict__ C1, void* __restrict__ C2,
               long long sCz, int ldc, int K, float scale,
               const float* __restrict__ bias)
{
  constexpr int ABUF = 256 * 32;        // elems per A (or B) K-tile
  constexpr int TBUF = 2 * ABUF;        // 16384 elems = 32 KB
  __shared__ ushort_t lds_[4 * TBUF] __attribute__((aligned(16)));   // 128 KB

  // XCD-aware bijective rect swizzle
  constexpr int BPR = RX * RY;
  const int gx = gridDim.x;
  const int lin = blockIdx.y * gx + blockIdx.x;
  const int xcd = lin & 7, s = lin >> 3;
  const int chunk = s / BPR, idx = s % BPR;
  const int rect = chunk * 8 + xcd;
  const int nrx = gx / RX;
  const int bx = (rect % nrx) * RX + (idx % RX);
  const int by = (rect / nrx) * RY + (idx / RX);

  const int z = blockIdx.z;
  const ushort_t* Ab = A  + (long long)z * sAz + (long long)by * 256 * lda;
  const ushort_t* Bb = Bm + (long long)z * sBz + (long long)bx * 256 * ldb;

  const int tid = threadIdx.x, wid = tid >> 6, lane = tid & 63;
  const int wr = wid >> 2, wc = wid & 3;     // wave out: rows wr*128, cols wc*64
  const int l15 = lane & 15;
  const int kq = (lane >> 4) * 8;            // frag k-offset within BK=32

  // staging: per wave 2 A-insts + 2 B-insts per tile; inst j covers 16 rows
  // (rows wid*32 + j*16 + lane>>2, col (lane&3)*8). LDS dest linear.
  const int srow = lane >> 2;
  const int scol = (lane & 3) * 8;
  const ushort_t* agA = Ab + (long long)(wid * 32 + srow) * lda + scol;
  const ushort_t* agB = Bb + (long long)(wid * 32 + srow) * ldb + scol;

  auto stage = [&](int t) {
    const int rb = (t & 3) * TBUF;
#pragma unroll
    for (int j = 0; j < 2; ++j) {
      __builtin_amdgcn_global_load_lds(
          (const __attribute__((address_space(1))) void*)(agA + (long long)(j * 16) * lda + t * 32),
          (__attribute__((address_space(3))) void*)(&lds_[rb + (wid * 32 + j * 16) * 32]),
          16, 0, 0);
      __builtin_amdgcn_global_load_lds(
          (const __attribute__((address_space(1))) void*)(agB + (long long)(j * 16) * ldb + t * 32),
          (__attribute__((address_space(3))) void*)(&lds_[rb + ABUF + (wid * 32 + j * 16) * 32]),
          16, 0, 0);
    }
  };

  f32x4 acc[8][4];
#pragma unroll
  for (int m = 0; m < 8; ++m)
#pragma unroll
    for (int n = 0; n < 4; ++n)
#pragma unroll
      for (int j = 0; j < 4; ++j) acc[m][n][j] = 0.f;

  const int NT = K >> 5;

  // prologue: stage tiles 0,1,2 (12 loads/wave); certify tile 0
  stage(0); stage(1); stage(2);
  asm volatile("s_waitcnt vmcnt(8)" ::: "memory");
  __builtin_amdgcn_s_barrier();
  __builtin_amdgcn_sched_barrier(0);

  bf16x8 af[8], bf[4];
  for (int t = 0; t < NT; ++t) {
    if (t + 3 < NT) stage(t + 3);
    __builtin_amdgcn_sched_barrier(0);

    const ushort_t* Al = &lds_[(t & 3) * TBUF] + (wr * 128) * 32;
    const ushort_t* Bl = &lds_[(t & 3) * TBUF + ABUF] + (wc * 64) * 32;
#pragma unroll
    for (int m = 0; m < 8; ++m) af[m] = *(const bf16x8*)(Al + (m * 16 + l15) * 32 + kq);
#pragma unroll
    for (int n = 0; n < 4; ++n) bf[n] = *(const bf16x8*)(Bl + (n * 16 + l15) * 32 + kq);

    __builtin_amdgcn_s_setprio(1);
#pragma unroll
    for (int m = 0; m < 8; ++m)
#pragma unroll
      for (int n = 0; n < 4; ++n)
        acc[m][n] = __builtin_amdgcn_mfma_f32_16x16x32_bf16(af[m], bf[n], acc[m][n], 0, 0, 0);
    __builtin_amdgcn_s_setprio(0);

    if (t < NT - 3)       asm volatile("s_waitcnt vmcnt(8)" ::: "memory");
    else if (t == NT - 3) asm volatile("s_waitcnt vmcnt(4)" ::: "memory");
    else if (t == NT - 2) asm volatile("s_waitcnt vmcnt(0)" ::: "memory");
    __builtin_amdgcn_s_barrier();
    __builtin_amdgcn_sched_barrier(0);
  }

  // epilogue: C/D layout col=lane&15, row=(lane>>4)*4+j
  const int r4 = (lane >> 4) * 4;
  const long long crow0 = (long long)by * 256 + wr * 128;
  const int ccol0 = bx * 256 + wc * 64;

  if constexpr (MODE == 1) {
    _Float16* C = (_Float16*)C0;
#pragma unroll
    for (int n = 0; n < 4; ++n) {
      const int cg = ccol0 + n * 16 + l15;
#pragma unroll
      for (int m = 0; m < 8; ++m)
#pragma unroll
        for (int j = 0; j < 4; ++j) {
          const long long rg = crow0 + m * 16 + r4 + j;
          C[(long long)z * sCz + rg * ldc + cg] = (_Float16)(acc[m][n][j] * scale);
        }
    }
  } else {
    const int sel = ccol0 >> 10;
#pragma unroll
    for (int n = 0; n < 4; ++n) {
      const int cg = ccol0 + n * 16 + l15;
      const int col = cg & 1023;
      const float badd = bias[cg];
      if (sel < 2) {
        ushort_t* outp = (ushort_t*)(sel == 0 ? C0 : C1);
#pragma unroll
        for (int m = 0; m < 8; ++m)
#pragma unroll
          for (int j = 0; j < 4; ++j) {
            const long long rg = crow0 + m * 16 + r4 + j;
            outp[rg * 1024 + col] = f2bf(acc[m][n][j] + badd);
          }
      } else {
        ushort_t* vt = (ushort_t*)C2;
#pragma unroll
        for (int m = 0; m < 8; ++m) {
          const long long rg = crow0 + m * 16 + r4;
          const long long b = rg >> 11, srw = rg & 2047;
          ushort4 o;
          o.x = f2bf(acc[m][n][0] + badd);
          o.y = f2bf(acc[m][n][1] + badd);
          o.z = f2bf(acc[m][n][2] + badd);
          o.w = f2bf(acc[m][n][3] + badd);
          *(ushort4*)&vt[b * 2097152 + (long long)col * 2048 + srw] = o;
        }
      }
    }
  }
}

// ---------------------------------------------------------------------------
// pv_gemm: 128x128 tile, 2-phase, 64 KB LDS, 2 blocks/CU (r9, proven).
// ---------------------------------------------------------------------------
template<int RX, int RY>
__global__ __launch_bounds__(512, 4)
void pv_gemm(const ushort_t* __restrict__ A, long long sAz, int lda,
             const ushort_t* __restrict__ Bm, long long sBz, int ldb,
             float* __restrict__ C0, long long sCz, int ldc, int K)
{
  constexpr int SLOT = 8192;
  constexpr int BUF  = 2 * SLOT;
  __shared__ ushort_t lds_[2 * BUF] __attribute__((aligned(16)));

  constexpr int BPR = RX * RY;
  const int gx = gridDim.x;
  const int lin = blockIdx.y * gx + blockIdx.x;
  const int xcd = lin & 7, s = lin >> 3;
  const int chunk = s / BPR, idx = s % BPR;
  const int rect = chunk * 8 + xcd;
  const int nrx = gx / RX;
  const int bx = (rect % nrx) * RX + (idx % RX);
  const int by = (rect / nrx) * RY + (idx / RX);

  const int z = blockIdx.z;
  const ushort_t* Ab = A  + (long long)z * sAz + (long long)by * 128 * lda;
  const ushort_t* Bb = Bm + (long long)z * sBz + (long long)bx * 128 * ldb;

  const int tid = threadIdx.x, wid = tid >> 6, lane = tid & 63;
  const int wr = wid >> 2, wc = wid & 3;
  const int l15 = lane & 15;
  const int kx0 = (((lane >> 4) + 0) ^ (l15 & 7)) * 8;
  const int kx1 = (((lane >> 4) + 4) ^ (l15 & 7)) * 8;
  const int srow = lane >> 3;
  const int scol = ((lane & 7) ^ (srow & 7)) * 8;

  const ushort_t* agA = Ab + (long long)(wid * 8 + srow) * lda + scol;
  const ushort_t* agB = Bb + (long long)(wid * 8 + srow) * ldb + scol;
  const long long jA = (long long)64 * lda, jB = (long long)64 * ldb;
  const int ldsA0 = wid * 512;
  const int ldsB0 = SLOT + wid * 512;

  auto stage = [&](const ushort_t* g, long long jstep, int ldsOff) {
#pragma unroll
    for (int j = 0; j < 2; ++j)
      __builtin_amdgcn_global_load_lds(
          (const __attribute__((address_space(1))) void*)(g + j * jstep),
          (__attribute__((address_space(3))) void*)(&lds_[ldsOff + j * 4096]),
          16, 0, 0);
  };

  f32x4 acc[4][2];
#pragma unroll
  for (int m = 0; m < 4; ++m)
#pragma unroll
    for (int n = 0; n < 2; ++n)
#pragma unroll
      for (int j = 0; j < 4; ++j) acc[m][n][j] = 0.f;

  stage(agA, jA, 0 * BUF + ldsA0); agA += 64;
  stage(agB, jB, 0 * BUF + ldsB0); agB += 64;
  stage(agA, jA, 1 * BUF + ldsA0); agA += 64;
  stage(agB, jB, 1 * BUF + ldsB0); agB += 64;
  asm volatile("s_waitcnt vmcnt(4)" ::: "memory");
  __builtin_amdgcn_s_barrier();

  const int NT = K >> 6;
  bf16x8 a0[4], a1[4], bf[2];

  for (int t = 0; t < NT; ++t) {
    const int q = t & 1;
    const ushort_t* Al = &lds_[q * BUF] + wr * 4096;
    const ushort_t* Bl = &lds_[q * BUF + SLOT] + wc * 2048;

#pragma unroll
    for (int m = 0; m < 4; ++m) a0[m] = *(const bf16x8*)(Al + (m * 16 + l15) * 64 + kx0);
#pragma unroll
    for (int n = 0; n < 2; ++n) bf[n] = *(const bf16x8*)(Bl + (n * 16 + l15) * 64 + kx0);
#pragma unroll
    for (int m = 0; m < 4; ++m) a1[m] = *(const bf16x8*)(Al + (m * 16 + l15) * 64 + kx1);
    __builtin_amdgcn_s_barrier();
    __builtin_amdgcn_s_setprio(1);
#pragma unroll
    for (int m = 0; m < 4; ++m)
#pragma unroll
      for (int n = 0; n < 2; ++n)
        acc[m][n] = __builtin_amdgcn_mfma_f32_16x16x32_bf16(a0[m], bf[n], acc[m][n], 0, 0, 0);
    __builtin_amdgcn_s_setprio(0);
    __builtin_amdgcn_s_barrier();

#pragma unroll
    for (int n = 0; n < 2; ++n) bf[n] = *(const bf16x8*)(Bl + (n * 16 + l15) * 64 + kx1);
    asm volatile("s_waitcnt lgkmcnt(0)" ::: "memory");
    __builtin_amdgcn_sched_barrier(0);
    if (t + 2 < NT) {
      stage(agA, jA, q * BUF + ldsA0); agA += 64;
      stage(agB, jB, q * BUF + ldsB0); agB += 64;
    }
    __builtin_amdgcn_s_barrier();
    __builtin_amdgcn_s_setprio(1);
#pragma unroll
    for (int m = 0; m < 4; ++m)
#pragma unroll
      for (int n = 0; n < 2; ++n)
        acc[m][n] = __builtin_amdgcn_mfma_f32_16x16x32_bf16(a1[m], bf[n], acc[m][n], 0, 0, 0);
    __builtin_amdgcn_s_setprio(0);
    if (t < NT - 2)       asm volatile("s_waitcnt vmcnt(4)" ::: "memory");
    else if (t == NT - 2) asm volatile("s_waitcnt vmcnt(0)" ::: "memory");
    __builtin_amdgcn_s_barrier();
  }

  const int r4 = (lane >> 4) * 4;
  const long long crow0 = (long long)by * 128 + wr * 64;
  const int ccol0 = bx * 128 + wc * 32;
#pragma unroll
  for (int n = 0; n < 2; ++n) {
    const int cg = ccol0 + n * 16 + l15;
#pragma unroll
    for (int m = 0; m < 4; ++m)
#pragma unroll
      for (int j = 0; j < 4; ++j) {
        const long long rg = crow0 + m * 16 + r4 + j;
        C0[(long long)z * sCz + rg * ldc + cg] = acc[m][n][j];
      }
  }
}

// ---------------------------------------------------------------------------
__global__ __launch_bounds__(256)
void cast_f32_bf16(const float* __restrict__ in, ushort_t* __restrict__ out, long long n)
{
  long long i = ((long long)blockIdx.x * blockDim.x + threadIdx.x) * 4;
  const long long stride = (long long)gridDim.x * blockDim.x * 4;
  for (; i < n; i += stride) {
    const float4 v = *(const float4*)&in[i];
    ushort4 o;
    o.x = f2bf(v.x); o.y = f2bf(v.y); o.z = f2bf(v.z); o.w = f2bf(v.w);
    *(ushort4*)&out[i] = o;
  }
}

__global__ __launch_bounds__(256)
void prep_w(const float* __restrict__ Wq, const float* __restrict__ Wk,
            const float* __restrict__ Wv, const float* __restrict__ bq,
            const float* __restrict__ bk, const float* __restrict__ bv,
            ushort_t* __restrict__ w3, float* __restrict__ bcat)
{
  const int which = blockIdx.x >> 10;
  const float* W = (which == 0) ? Wq : (which == 1) ? Wk : Wv;
  const long long i = ((long long)(blockIdx.x & 1023) * 256 + threadIdx.x) * 4;
  const float4 v = *(const float4*)&W[i];
  ushort4 o;
  o.x = f2bf(v.x); o.y = f2bf(v.y); o.z = f2bf(v.z); o.w = f2bf(v.w);
  *(ushort4*)&w3[(long long)which * 1024 * 1024 + i] = o;
  const int g = blockIdx.x * 256 + threadIdx.x;
  if (g < 3072) bcat[g] = (g < 1024) ? bq[g] : (g < 2048) ? bk[g - 1024] : bv[g - 2048];
}

// row softmax over 2048 fp16 -> bf16, one block (256 thr) per row
__global__ __launch_bounds__(256)
void softmax2048(const _Float16* __restrict__ Sc, ushort_t* __restrict__ P)
{
  const long long row = blockIdx.x;
  const _Float16* s = Sc + row * 2048;
  const int tid = threadIdx.x;
  const int wave = tid >> 6, lane = tid & 63;

  const h8 a = *(const h8*)&s[tid * 8];
  float f[8];
#pragma unroll
  for (int i = 0; i < 8; ++i) f[i] = (float)a[i];
  float m = fmaxf(fmaxf(fmaxf(f[0], f[1]), fmaxf(f[2], f[3])),
                  fmaxf(fmaxf(f[4], f[5]), fmaxf(f[6], f[7])));
#pragma unroll
  for (int off = 32; off > 0; off >>= 1) m = fmaxf(m, __shfl_xor(m, off));
  __shared__ float redm[4], reds[4];
  if (lane == 0) redm[wave] = m;
  __syncthreads();
  m = fmaxf(fmaxf(redm[0], redm[1]), fmaxf(redm[2], redm[3]));

  float e[8];
#pragma unroll
  for (int i = 0; i < 8; ++i) e[i] = __expf(f[i] - m);
  float sum = ((e[0] + e[1]) + (e[2] + e[3])) + ((e[4] + e[5]) + (e[6] + e[7]));
#pragma unroll
  for (int off = 32; off > 0; off >>= 1) sum += __shfl_xor(sum, off);
  if (lane == 0) reds[wave] = sum;
  __syncthreads();
  sum = (reds[0] + reds[1]) + (reds[2] + reds[3]);
  const float inv = 1.0f / sum;

  short8v o;
#pragma unroll
  for (int i = 0; i < 8; ++i) o[i] = (short)f2bf(e[i] * inv);
  *(short8v*)&P[row * 2048 + tid * 8] = o;
}

// ---------------------------------------------------------------------------
extern "C" void kernel_launch(void* const* d_in, const int* in_sizes, int n_in,
                              void* d_out, int out_size, void* d_ws, size_t ws_size,
                              hipStream_t stream)
{
  constexpr int B = 4, S = 2048, D = 1024;
  constexpr long long MT = (long long)B * S;
  constexpr long long SD = (long long)S * D;
  constexpr long long SS = (long long)S * S;

  const float* x  = (const float*)d_in[0];
  const float* Wq = (const float*)d_in[1];
  const float* bq = (const float*)d_in[2];
  const float* Wk = (const float*)d_in[3];
  const float* bk = (const float*)d_in[4];
  const float* Wv = (const float*)d_in[5];
  const float* bv = (const float*)d_in[6];
  float* out = (float*)d_out;

  // ws layout (bytes)
  char* base = (char*)d_ws;
  ushort_t*  q       = (ushort_t*)(base);               // 16777216
  ushort_t*  k       = (ushort_t*)(base + 16777216);    // 16777216
  ushort_t*  vt      = (ushort_t*)(base + 33554432);    // 16777216  [4][1024][2048]
  _Float16*  scores  = (_Float16*)(base + 50331648);    // 33554432  fp16
  ushort_t*  P       = (ushort_t*)(base + 117440512);   // 33554432
  ushort_t*  xb      = (ushort_t*)(base + 83886080);    // 16777216
  ushort_t*  w3      = (ushort_t*)(base + 100663296);   // 6291456
  float*     bcat    = (float*)   (base + 106954752);   // 12288

  // 1) casts
  cast_f32_bf16<<<2048, 256, 0, stream>>>(x, xb, MT * D);
  prep_w<<<3072, 256, 0, stream>>>(Wq, Wk, Wv, bq, bk, bv, w3, bcat);

  // 2) fused QKV projection (ring-4) -> q, k, vt(transposed)
  ring_gemm<2, 4, 2><<<dim3(12, 32, 1), 512, 0, stream>>>(
      xb, 0, D, w3, 0, D, q, k, vt, 0, 1024, D, 1.f, bcat);

  // 3) QK^T (ring-4): scores[z] = (q @ k^T) / 32  (fp16 out)
  ring_gemm<1, 4, 2><<<dim3(8, 8, 4), 512, 0, stream>>>(
      q, SD, D, k, SD, D, scores, nullptr, nullptr, SS, S, D, 0.03125f, nullptr);

  // 4) softmax rows (fp16 in, bf16 out)
  softmax2048<<<MT, 256, 0, stream>>>(scores, P);

  // 5) PV: out[z] = P @ vt^T
  pv_gemm<2, 4><<<dim3(8, 16, 4), 512, 0, stream>>>(
      P, SS, S, vt, (long long)D * S, S, out, SD, D, S);
}

// Round 11
// 184.680 us; speedup vs baseline: 1.0176x; 1.0176x over previous
//
#include <hip/hip_runtime.h>

// Attention_13632226198096: B=4, S=2048, D=1024 fp32 single-head attention.
// Round 11: proj moved onto the 256x256 4-phase prefetch-2 structure
// (per-wave 128x64 — the only MFMA-balanced frag economy: 24 b128/64 MFMA),
// with MODE-2 epilogue (q/k split + v^T + bias) and 4x4 XCD rect.
// QK: same structure MODE 1 (fp16 scores). PV: 128^2 2-phase (r9).
// Conflict-free row&7 XOR LDS swizzle everywhere. r10's BK=32 ring reverted
// (64-B rows span only 16 banks -> 4.7e6 conflicts).

typedef unsigned short ushort_t;
typedef __bf16 bf16x8 __attribute__((ext_vector_type(8)));
typedef float f32x4 __attribute__((ext_vector_type(4)));
typedef _Float16 h8 __attribute__((ext_vector_type(8)));
typedef short short8v __attribute__((ext_vector_type(8)));

__device__ __forceinline__ unsigned short f2bf(float f) {
  unsigned u = __builtin_bit_cast(unsigned, f);
  u += 0x7fffu + ((u >> 16) & 1u);
  return (unsigned short)(u >> 16);
}

// ---------------------------------------------------------------------------
// gemm256: 256x256 tile, BK=64, 512 thr (8 waves 2Mx4N, 128x64/wave).
// 4 phases/K-tile, 16 MFMA each; A(t+2)+B(t+2) staged in ph4 after lgkm
// drain (race-free); vmcnt(8) steady (tile t+1 certified, full-tile cover).
// MODE 1: fp16 C0 = scale*acc. MODE 2: proj split -> q/k bf16 + v^T into C2.
// ---------------------------------------------------------------------------
template<int MODE, int RX, int RY>
__global__ __launch_bounds__(512, 1)
void gemm256(const ushort_t* __restrict__ A, long long sAz, int lda,
             const ushort_t* __restrict__ Bm, long long sBz, int ldb,
             void* __restrict__ C0, void* __restrict__ C1, void* __restrict__ C2,
             long long sCz, int ldc, int K, float scale,
             const float* __restrict__ bias)
{
  constexpr int AH = 8192, BH = 8192, BUF = 2 * AH + 2 * BH;
  constexpr int BPR = RX * RY;
  __shared__ ushort_t lds_[2 * BUF] __attribute__((aligned(16)));

  const int gx = gridDim.x;
  const int lin = blockIdx.y * gx + blockIdx.x;
  const int xcd = lin & 7, s = lin >> 3;
  const int chunk = s / BPR, idx = s % BPR;
  const int rect = chunk * 8 + xcd;
  const int nrx = gx / RX;
  const int bx = (rect % nrx) * RX + (idx % RX);
  const int by = (rect / nrx) * RY + (idx / RX);

  const int z = blockIdx.z;
  const ushort_t* Ab = A  + (long long)z * sAz + (long long)by * 256 * lda;
  const ushort_t* Bb = Bm + (long long)z * sBz + (long long)bx * 256 * ldb;

  const int tid = threadIdx.x, wid = tid >> 6, lane = tid & 63;
  const int wr = wid >> 2, wc = wid & 3;
  const int l15 = lane & 15;
  const int kx0 = (((lane >> 4) + 0) ^ (l15 & 7)) * 8;
  const int kx1 = (((lane >> 4) + 4) ^ (l15 & 7)) * 8;
  const int srow = lane >> 3;
  const int scol = ((lane & 7) ^ (srow & 7)) * 8;

  const ushort_t* agA = Ab + (long long)(wid * 16 + srow) * lda + scol;
  const ushort_t* agB = Bb + (long long)(wid * 16 + srow) * ldb + scol;

  auto stageA = [&](int q) {
#pragma unroll
    for (int h = 0; h < 2; ++h)
#pragma unroll
      for (int j = 0; j < 2; ++j)
        __builtin_amdgcn_global_load_lds(
            (const __attribute__((address_space(1))) void*)(agA + (long long)(h * 128 + j * 8) * lda),
            (__attribute__((address_space(3))) void*)
              (&lds_[q * BUF + h * AH + (wid * 128 + j * 64) * 8]),
            16, 0, 0);
  };
  auto stageB = [&](int q) {
#pragma unroll
    for (int h = 0; h < 2; ++h)
#pragma unroll
      for (int j = 0; j < 2; ++j)
        __builtin_amdgcn_global_load_lds(
            (const __attribute__((address_space(1))) void*)(agB + (long long)(h * 128 + j * 8) * ldb),
            (__attribute__((address_space(3))) void*)
              (&lds_[q * BUF + 2 * AH + h * BH + (wid * 128 + j * 64) * 8]),
            16, 0, 0);
  };

  f32x4 acc[8][4];
#pragma unroll
  for (int m = 0; m < 8; ++m)
#pragma unroll
    for (int n = 0; n < 4; ++n)
#pragma unroll
      for (int j = 0; j < 4; ++j) acc[m][n][j] = 0.f;

  stageA(0); stageB(0); agA += 64; agB += 64;
  stageA(1); stageB(1); agA += 64; agB += 64;
  asm volatile("s_waitcnt vmcnt(8)" ::: "memory");
  __builtin_amdgcn_s_barrier();

  const int NT = K >> 6;
  bf16x8 af[4], bf[4];

  for (int t = 0; t < NT; ++t) {
    const int q = t & 1;
    const ushort_t* Al = &lds_[q * BUF + wr * AH];
    const ushort_t* Bl = &lds_[q * BUF + 2 * AH + (wc >> 1) * BH + (wc & 1) * 4096];

    // ph1: k0, m0-3 + all B@k0
#pragma unroll
    for (int n = 0; n < 4; ++n) bf[n] = *(const bf16x8*)(Bl + (n * 16 + l15) * 64 + kx0);
#pragma unroll
    for (int m = 0; m < 4; ++m) af[m] = *(const bf16x8*)(Al + (m * 16 + l15) * 64 + kx0);
    __builtin_amdgcn_s_barrier();
    __builtin_amdgcn_s_setprio(1);
#pragma unroll
    for (int m = 0; m < 4; ++m)
#pragma unroll
      for (int n = 0; n < 4; ++n)
        acc[m][n] = __builtin_amdgcn_mfma_f32_16x16x32_bf16(af[m], bf[n], acc[m][n], 0, 0, 0);
    __builtin_amdgcn_s_setprio(0);
    __builtin_amdgcn_s_barrier();

    // ph2: k0, m4-7
#pragma unroll
    for (int m = 0; m < 4; ++m) af[m] = *(const bf16x8*)(Al + ((4 + m) * 16 + l15) * 64 + kx0);
    __builtin_amdgcn_s_barrier();
    __builtin_amdgcn_s_setprio(1);
#pragma unroll
    for (int m = 0; m < 4; ++m)
#pragma unroll
      for (int n = 0; n < 4; ++n)
        acc[4 + m][n] = __builtin_amdgcn_mfma_f32_16x16x32_bf16(af[m], bf[n], acc[4 + m][n], 0, 0, 0);
    __builtin_amdgcn_s_setprio(0);
    __builtin_amdgcn_s_barrier();

    // ph3: k1, m0-3
#pragma unroll
    for (int n = 0; n < 4; ++n) bf[n] = *(const bf16x8*)(Bl + (n * 16 + l15) * 64 + kx1);
#pragma unroll
    for (int m = 0; m < 4; ++m) af[m] = *(const bf16x8*)(Al + (m * 16 + l15) * 64 + kx1);
    __builtin_amdgcn_s_barrier();
    __builtin_amdgcn_s_setprio(1);
#pragma unroll
    for (int m = 0; m < 4; ++m)
#pragma unroll
      for (int n = 0; n < 4; ++n)
        acc[m][n] = __builtin_amdgcn_mfma_f32_16x16x32_bf16(af[m], bf[n], acc[m][n], 0, 0, 0);
    __builtin_amdgcn_s_setprio(0);
    __builtin_amdgcn_s_barrier();

    // ph4: k1, m4-7; lgkm drain then stage A(t+2)+B(t+2) into buf q
#pragma unroll
    for (int m = 0; m < 4; ++m) af[m] = *(const bf16x8*)(Al + ((4 + m) * 16 + l15) * 64 + kx1);
    asm volatile("s_waitcnt lgkmcnt(0)" ::: "memory");
    __builtin_amdgcn_sched_barrier(0);
    if (t + 2 < NT) { stageA(q); stageB(q); agA += 64; agB += 64; }
    __builtin_amdgcn_s_barrier();
    __builtin_amdgcn_s_setprio(1);
#pragma unroll
    for (int m = 0; m < 4; ++m)
#pragma unroll
      for (int n = 0; n < 4; ++n)
        acc[4 + m][n] = __builtin_amdgcn_mfma_f32_16x16x32_bf16(af[m], bf[n], acc[4 + m][n], 0, 0, 0);
    __builtin_amdgcn_s_setprio(0);
    if (t < NT - 2)       asm volatile("s_waitcnt vmcnt(8)" ::: "memory");
    else if (t == NT - 2) asm volatile("s_waitcnt vmcnt(0)" ::: "memory");
    __builtin_amdgcn_s_barrier();
  }

  // epilogue: C/D layout col=lane&15, row=(lane>>4)*4+j
  const int r4 = (lane >> 4) * 4;
  const long long crow0 = (long long)by * 256 + wr * 128;
  const int ccol0 = bx * 256 + wc * 64;

  if constexpr (MODE == 1) {
    _Float16* C = (_Float16*)C0;
#pragma unroll
    for (int n = 0; n < 4; ++n) {
      const int cg = ccol0 + n * 16 + l15;
#pragma unroll
      for (int m = 0; m < 8; ++m)
#pragma unroll
        for (int j = 0; j < 4; ++j) {
          const long long rg = crow0 + m * 16 + r4 + j;
          C[(long long)z * sCz + rg * ldc + cg] = (_Float16)(acc[m][n][j] * scale);
        }
    }
  } else {
    // MODE 2: proj split. Block spans 256 cols within one 1024-col group.
    const int sel = ccol0 >> 10;
#pragma unroll
    for (int n = 0; n < 4; ++n) {
      const int cg = ccol0 + n * 16 + l15;
      const int col = cg & 1023;
      const float badd = bias[cg];
      if (sel < 2) {
        ushort_t* outp = (ushort_t*)(sel == 0 ? C0 : C1);
#pragma unroll
        for (int m = 0; m < 8; ++m)
#pragma unroll
          for (int j = 0; j < 4; ++j) {
            const long long rg = crow0 + m * 16 + r4 + j;
            outp[rg * 1024 + col] = f2bf(acc[m][n][j] + badd);
          }
      } else {
        ushort_t* vt = (ushort_t*)C2;
#pragma unroll
        for (int m = 0; m < 8; ++m) {
          const long long rg = crow0 + m * 16 + r4;
          const long long b = rg >> 11, srw = rg & 2047;
          ushort4 o;
          o.x = f2bf(acc[m][n][0] + badd);
          o.y = f2bf(acc[m][n][1] + badd);
          o.z = f2bf(acc[m][n][2] + badd);
          o.w = f2bf(acc[m][n][3] + badd);
          *(ushort4*)&vt[b * 2097152 + (long long)col * 2048 + srw] = o;
        }
      }
    }
  }
}

// ---------------------------------------------------------------------------
// pv_gemm: 128x128 tile, 2-phase, 64 KB LDS, 2 blocks/CU (r9, proven).
// ---------------------------------------------------------------------------
template<int RX, int RY>
__global__ __launch_bounds__(512, 4)
void pv_gemm(const ushort_t* __restrict__ A, long long sAz, int lda,
             const ushort_t* __restrict__ Bm, long long sBz, int ldb,
             float* __restrict__ C0, long long sCz, int ldc, int K)
{
  constexpr int SLOT = 8192;
  constexpr int BUF  = 2 * SLOT;
  __shared__ ushort_t lds_[2 * BUF] __attribute__((aligned(16)));

  constexpr int BPR = RX * RY;
  const int gx = gridDim.x;
  const int lin = blockIdx.y * gx + blockIdx.x;
  const int xcd = lin & 7, s = lin >> 3;
  const int chunk = s / BPR, idx = s % BPR;
  const int rect = chunk * 8 + xcd;
  const int nrx = gx / RX;
  const int bx = (rect % nrx) * RX + (idx % RX);
  const int by = (rect / nrx) * RY + (idx / RX);

  const int z = blockIdx.z;
  const ushort_t* Ab = A  + (long long)z * sAz + (long long)by * 128 * lda;
  const ushort_t* Bb = Bm + (long long)z * sBz + (long long)bx * 128 * ldb;

  const int tid = threadIdx.x, wid = tid >> 6, lane = tid & 63;
  const int wr = wid >> 2, wc = wid & 3;
  const int l15 = lane & 15;
  const int kx0 = (((lane >> 4) + 0) ^ (l15 & 7)) * 8;
  const int kx1 = (((lane >> 4) + 4) ^ (l15 & 7)) * 8;
  const int srow = lane >> 3;
  const int scol = ((lane & 7) ^ (srow & 7)) * 8;

  const ushort_t* agA = Ab + (long long)(wid * 8 + srow) * lda + scol;
  const ushort_t* agB = Bb + (long long)(wid * 8 + srow) * ldb + scol;
  const long long jA = (long long)64 * lda, jB = (long long)64 * ldb;
  const int ldsA0 = wid * 512;
  const int ldsB0 = SLOT + wid * 512;

  auto stage = [&](const ushort_t* g, long long jstep, int ldsOff) {
#pragma unroll
    for (int j = 0; j < 2; ++j)
      __builtin_amdgcn_global_load_lds(
          (const __attribute__((address_space(1))) void*)(g + j * jstep),
          (__attribute__((address_space(3))) void*)(&lds_[ldsOff + j * 4096]),
          16, 0, 0);
  };

  f32x4 acc[4][2];
#pragma unroll
  for (int m = 0; m < 4; ++m)
#pragma unroll
    for (int n = 0; n < 2; ++n)
#pragma unroll
      for (int j = 0; j < 4; ++j) acc[m][n][j] = 0.f;

  stage(agA, jA, 0 * BUF + ldsA0); agA += 64;
  stage(agB, jB, 0 * BUF + ldsB0); agB += 64;
  stage(agA, jA, 1 * BUF + ldsA0); agA += 64;
  stage(agB, jB, 1 * BUF + ldsB0); agB += 64;
  asm volatile("s_waitcnt vmcnt(4)" ::: "memory");
  __builtin_amdgcn_s_barrier();

  const int NT = K >> 6;
  bf16x8 a0[4], a1[4], bf[2];

  for (int t = 0; t < NT; ++t) {
    const int q = t & 1;
    const ushort_t* Al = &lds_[q * BUF] + wr * 4096;
    const ushort_t* Bl = &lds_[q * BUF + SLOT] + wc * 2048;

#pragma unroll
    for (int m = 0; m < 4; ++m) a0[m] = *(const bf16x8*)(Al + (m * 16 + l15) * 64 + kx0);
#pragma unroll
    for (int n = 0; n < 2; ++n) bf[n] = *(const bf16x8*)(Bl + (n * 16 + l15) * 64 + kx0);
#pragma unroll
    for (int m = 0; m < 4; ++m) a1[m] = *(const bf16x8*)(Al + (m * 16 + l15) * 64 + kx1);
    __builtin_amdgcn_s_barrier();
    __builtin_amdgcn_s_setprio(1);
#pragma unroll
    for (int m = 0; m < 4; ++m)
#pragma unroll
      for (int n = 0; n < 2; ++n)
        acc[m][n] = __builtin_amdgcn_mfma_f32_16x16x32_bf16(a0[m], bf[n], acc[m][n], 0, 0, 0);
    __builtin_amdgcn_s_setprio(0);
    __builtin_amdgcn_s_barrier();

#pragma unroll
    for (int n = 0; n < 2; ++n) bf[n] = *(const bf16x8*)(Bl + (n * 16 + l15) * 64 + kx1);
    asm volatile("s_waitcnt lgkmcnt(0)" ::: "memory");
    __builtin_amdgcn_sched_barrier(0);
    if (t + 2 < NT) {
      stage(agA, jA, q * BUF + ldsA0); agA += 64;
      stage(agB, jB, q * BUF + ldsB0); agB += 64;
    }
    __builtin_amdgcn_s_barrier();
    __builtin_amdgcn_s_setprio(1);
#pragma unroll
    for (int m = 0; m < 4; ++m)
#pragma unroll
      for (int n = 0; n < 2; ++n)
        acc[m][n] = __builtin_amdgcn_mfma_f32_16x16x32_bf16(a1[m], bf[n], acc[m][n], 0, 0, 0);
    __builtin_amdgcn_s_setprio(0);
    if (t < NT - 2)       asm volatile("s_waitcnt vmcnt(4)" ::: "memory");
    else if (t == NT - 2) asm volatile("s_waitcnt vmcnt(0)" ::: "memory");
    __builtin_amdgcn_s_barrier();
  }

  const int r4 = (lane >> 4) * 4;
  const long long crow0 = (long long)by * 128 + wr * 64;
  const int ccol0 = bx * 128 + wc * 32;
#pragma unroll
  for (int n = 0; n < 2; ++n) {
    const int cg = ccol0 + n * 16 + l15;
#pragma unroll
    for (int m = 0; m < 4; ++m)
#pragma unroll
      for (int j = 0; j < 4; ++j) {
        const long long rg = crow0 + m * 16 + r4 + j;
        C0[(long long)z * sCz + rg * ldc + cg] = acc[m][n][j];
      }
  }
}

// ---------------------------------------------------------------------------
__global__ __launch_bounds__(256)
void cast_f32_bf16(const float* __restrict__ in, ushort_t* __restrict__ out, long long n)
{
  long long i = ((long long)blockIdx.x * blockDim.x + threadIdx.x) * 4;
  const long long stride = (long long)gridDim.x * blockDim.x * 4;
  for (; i < n; i += stride) {
    const float4 v = *(const float4*)&in[i];
    ushort4 o;
    o.x = f2bf(v.x); o.y = f2bf(v.y); o.z = f2bf(v.z); o.w = f2bf(v.w);
    *(ushort4*)&out[i] = o;
  }
}

__global__ __launch_bounds__(256)
void prep_w(const float* __restrict__ Wq, const float* __restrict__ Wk,
            const float* __restrict__ Wv, const float* __restrict__ bq,
            const float* __restrict__ bk, const float* __restrict__ bv,
            ushort_t* __restrict__ w3, float* __restrict__ bcat)
{
  const int which = blockIdx.x >> 10;
  const float* W = (which == 0) ? Wq : (which == 1) ? Wk : Wv;
  const long long i = ((long long)(blockIdx.x & 1023) * 256 + threadIdx.x) * 4;
  const float4 v = *(const float4*)&W[i];
  ushort4 o;
  o.x = f2bf(v.x); o.y = f2bf(v.y); o.z = f2bf(v.z); o.w = f2bf(v.w);
  *(ushort4*)&w3[(long long)which * 1024 * 1024 + i] = o;
  const int g = blockIdx.x * 256 + threadIdx.x;
  if (g < 3072) bcat[g] = (g < 1024) ? bq[g] : (g < 2048) ? bk[g - 1024] : bv[g - 2048];
}

// row softmax over 2048 fp16 -> bf16, one block (256 thr) per row
__global__ __launch_bounds__(256)
void softmax2048(const _Float16* __restrict__ Sc, ushort_t* __restrict__ P)
{
  const long long row = blockIdx.x;
  const _Float16* s = Sc + row * 2048;
  const int tid = threadIdx.x;
  const int wave = tid >> 6, lane = tid & 63;

  const h8 a = *(const h8*)&s[tid * 8];
  float f[8];
#pragma unroll
  for (int i = 0; i < 8; ++i) f[i] = (float)a[i];
  float m = fmaxf(fmaxf(fmaxf(f[0], f[1]), fmaxf(f[2], f[3])),
                  fmaxf(fmaxf(f[4], f[5]), fmaxf(f[6], f[7])));
#pragma unroll
  for (int off = 32; off > 0; off >>= 1) m = fmaxf(m, __shfl_xor(m, off));
  __shared__ float redm[4], reds[4];
  if (lane == 0) redm[wave] = m;
  __syncthreads();
  m = fmaxf(fmaxf(redm[0], redm[1]), fmaxf(redm[2], redm[3]));

  float e[8];
#pragma unroll
  for (int i = 0; i < 8; ++i) e[i] = __expf(f[i] - m);
  float sum = ((e[0] + e[1]) + (e[2] + e[3])) + ((e[4] + e[5]) + (e[6] + e[7]));
#pragma unroll
  for (int off = 32; off > 0; off >>= 1) sum += __shfl_xor(sum, off);
  if (lane == 0) reds[wave] = sum;
  __syncthreads();
  sum = (reds[0] + reds[1]) + (reds[2] + reds[3]);
  const float inv = 1.0f / sum;

  short8v o;
#pragma unroll
  for (int i = 0; i < 8; ++i) o[i] = (short)f2bf(e[i] * inv);
  *(short8v*)&P[row * 2048 + tid * 8] = o;
}

// ---------------------------------------------------------------------------
extern "C" void kernel_launch(void* const* d_in, const int* in_sizes, int n_in,
                              void* d_out, int out_size, void* d_ws, size_t ws_size,
                              hipStream_t stream)
{
  constexpr int B = 4, S = 2048, D = 1024;
  constexpr long long MT = (long long)B * S;
  constexpr long long SD = (long long)S * D;
  constexpr long long SS = (long long)S * S;

  const float* x  = (const float*)d_in[0];
  const float* Wq = (const float*)d_in[1];
  const float* bq = (const float*)d_in[2];
  const float* Wk = (const float*)d_in[3];
  const float* bk = (const float*)d_in[4];
  const float* Wv = (const float*)d_in[5];
  const float* bv = (const float*)d_in[6];
  float* out = (float*)d_out;

  // ws layout (bytes)
  char* base = (char*)d_ws;
  ushort_t*  q       = (ushort_t*)(base);               // 16777216
  ushort_t*  k       = (ushort_t*)(base + 16777216);    // 16777216
  ushort_t*  vt      = (ushort_t*)(base + 33554432);    // 16777216  [4][1024][2048]
  _Float16*  scores  = (_Float16*)(base + 50331648);    // 33554432  fp16
  ushort_t*  P       = (ushort_t*)(base + 117440512);   // 33554432
  ushort_t*  xb      = (ushort_t*)(base + 83886080);    // 16777216
  ushort_t*  w3      = (ushort_t*)(base + 100663296);   // 6291456
  float*     bcat    = (float*)   (base + 106954752);   // 12288

  // 1) casts
  cast_f32_bf16<<<2048, 256, 0, stream>>>(x, xb, MT * D);
  prep_w<<<3072, 256, 0, stream>>>(Wq, Wk, Wv, bq, bk, bv, w3, bcat);

  // 2) fused QKV projection (256^2 4-phase) -> q, k, vt(transposed)
  gemm256<2, 4, 4><<<dim3(12, 32, 1), 512, 0, stream>>>(
      xb, 0, D, w3, 0, D, q, k, vt, 0, 1024, D, 1.f, bcat);

  // 3) QK^T (256^2 4-phase): scores[z] = (q @ k^T) / 32  (fp16 out)
  gemm256<1, 4, 2><<<dim3(8, 8, 4), 512, 0, stream>>>(
      q, SD, D, k, SD, D, scores, nullptr, nullptr, SS, S, D, 0.03125f, nullptr);

  // 4) softmax rows (fp16 in, bf16 out)
  softmax2048<<<MT, 256, 0, stream>>>(scores, P);

  // 5) PV: out[z] = P @ vt^T
  pv_gemm<2, 4><<<dim3(8, 16, 4), 512, 0, stream>>>(
      P, SS, S, vt, (long long)D * S, S, out, SD, D, S);
}